// Round 1
// baseline (918.867 us; speedup 1.0000x reference)
//
#include <hip/hip_runtime.h>

// Problem constants
#define NB 8
#define NN 5000
#define NR 12      // P == Q == 12 rows
#define DM 64      // model dim
// 40,000 independent (b,n) units; one wave (64 lanes) each.
// Block = 512 threads = 8 waves; grid = 5000 blocks -> exact cover.

__device__ __forceinline__ void gl_lds4(const float* g, const float* l) {
  // async global->LDS, 4 B per lane; LDS dest is wave-uniform base + lane*4
  __builtin_amdgcn_global_load_lds((const __attribute__((address_space(1))) void*)g,
                                   (__attribute__((address_space(3))) void*)l, 4, 0, 0);
}

// C[r][lane] = act( bias[lane] + sum_j rows[r][j] * W[lane][j] ),  r = 0..11
// wt is the jb-blocked transposed copy: wt4[jb*64 + o] = float4(W[o][4jb..4jb+3])
template <bool RELU>
__device__ __forceinline__ void gemm12(const float* __restrict__ row0,
                                       const float* __restrict__ wt,
                                       int lane, float bias, float outv[NR])
{
  float acc[NR];
#pragma unroll
  for (int r = 0; r < NR; ++r) acc[r] = bias;
  const float4* w4p = (const float4*)wt;
#pragma unroll
  for (int jb = 0; jb < 16; ++jb) {
    float4 w = w4p[jb * 64 + lane];           // sequential 1 KiB wave read, conflict-free
#pragma unroll
    for (int r = 0; r < NR; ++r) {
      float4 s = *(const float4*)(row0 + r * DM + jb * 4);  // broadcast read
      acc[r] = fmaf(s.x, w.x, acc[r]);
      acc[r] = fmaf(s.y, w.y, acc[r]);
      acc[r] = fmaf(s.z, w.z, acc[r]);
      acc[r] = fmaf(s.w, w.w, acc[r]);
    }
  }
#pragma unroll
  for (int r = 0; r < NR; ++r) outv[r] = RELU ? fmaxf(acc[r], 0.0f) : acc[r];
}

__global__ __launch_bounds__(512, 1)
void fused_attn_kernel(const float* __restrict__ X,  const float* __restrict__ SP,
                       const float* __restrict__ SQ,
                       const float* __restrict__ W21, const float* __restrict__ b21,
                       const float* __restrict__ W22, const float* __restrict__ b22,
                       const float* __restrict__ W23, const float* __restrict__ b23,
                       const float* __restrict__ W24, const float* __restrict__ b24,
                       const float* __restrict__ W25, const float* __restrict__ b25,
                       float* __restrict__ out)
{
  __shared__ __align__(16) float wlds[5 * DM * DM];          // 80 KiB
  __shared__ __align__(16) float stage[8 * 36 * DM];         // 72 KiB (8 waves x 36 rows)

  const int tid  = threadIdx.x;
  const int lane = tid & 63;
  const int wv   = tid >> 6;

  // ---- one-time per block: weights -> LDS, transposed-blocked ----
  {
    const float* Ws[5] = {W21, W22, W23, W24, W25};
#pragma unroll
    for (int m = 0; m < 5; ++m) {
      const float4* src = (const float4*)Ws[m];
      float4* dst = (float4*)&wlds[m * DM * DM];
      // 1024 float4 per matrix, 512 threads -> 2 each; coalesced global read
      for (int f = tid; f < 1024; f += 512) {
        int o = f >> 4, jb = f & 15;
        dst[jb * 64 + o] = src[f];             // one-time scattered LDS write
      }
    }
  }
  float bias0 = b21[lane], bias1 = b22[lane], bias2 = b23[lane];
  float bias3 = b24[lane], bias4 = b25[lane];
  __syncthreads();

  // ---- my (b, n) unit ----
  const int g = blockIdx.x * 8 + wv;           // 0 .. 39999 exactly
  const int b = g / NN;
  const int n = g - b * NN;

  float* st = &stage[wv * 36 * DM];

  // stage 36 input rows (12 per tensor), coalesced 256 B each
#pragma unroll
  for (int r = 0; r < NR; ++r) {
    int off = ((b * NR + r) * NN + n) * DM + lane;
    gl_lds4(SQ + off, st + (0 + r) * DM);
    gl_lds4(SP + off, st + (12 + r) * DM);
    gl_lds4(X  + off, st + (24 + r) * DM);
  }
  asm volatile("s_waitcnt vmcnt(0)" ::: "memory");

  // ---- projections (lane = output column) ----
  float q[NR], k[NR], v[NR];
  gemm12<true>(st + 0 * DM,  wlds + 0 * DM * DM, lane, bias0, q);
  gemm12<true>(st + 12 * DM, wlds + 1 * DM * DM, lane, bias1, k);
  gemm12<true>(st + 24 * DM, wlds + 2 * DM * DM, lane, bias2, v);

  // ---- 8-head attention over time axis (head = lane>>3, dim = lane&7) ----
  const float scale = 0.35355339059327373f;    // 1/sqrt(8)
  float o_[NR];
#pragma unroll
  for (int qi = 0; qi < NR; ++qi) {
    float s[NR];
#pragma unroll
    for (int pi = 0; pi < NR; ++pi) s[pi] = q[qi] * k[pi];
    // butterfly sum over the 8 lanes of this head group
#pragma unroll
    for (int m = 1; m < 8; m <<= 1) {
#pragma unroll
      for (int pi = 0; pi < NR; ++pi) s[pi] += __shfl_xor(s[pi], m, 64);
    }
    // softmax over pi (replicated in all 8 lanes of the group) + PV
    float mx = s[0];
#pragma unroll
    for (int pi = 1; pi < NR; ++pi) mx = fmaxf(mx, s[pi]);
    float sum = 0.0f, t = 0.0f;
#pragma unroll
    for (int pi = 0; pi < NR; ++pi) {
      float e = __expf((s[pi] - mx) * scale);
      sum += e;
      t = fmaf(e, v[pi], t);
    }
    o_[qi] = t / sum;
  }

  // ---- output FFN via LDS round-trip (within-wave; DS is in-order per wave) ----
#pragma unroll
  for (int qi = 0; qi < NR; ++qi) st[qi * DM + lane] = o_[qi];
  asm volatile("s_waitcnt lgkmcnt(0)" ::: "memory");

  float h[NR];
  gemm12<true>(st, wlds + 3 * DM * DM, lane, bias3, h);

#pragma unroll
  for (int qi = 0; qi < NR; ++qi) st[(12 + qi) * DM + lane] = h[qi];
  asm volatile("s_waitcnt lgkmcnt(0)" ::: "memory");

  float y[NR];
  gemm12<false>(st + 12 * DM, wlds + 4 * DM * DM, lane, bias4, y);

  // ---- store [B,Q,N,D], coalesced 256 B rows ----
#pragma unroll
  for (int qi = 0; qi < NR; ++qi)
    out[((b * NR + qi) * NN + n) * DM + lane] = y[qi];
}

extern "C" void kernel_launch(void* const* d_in, const int* in_sizes, int n_in,
                              void* d_out, int out_size, void* d_ws, size_t ws_size,
                              hipStream_t stream) {
  const float* X   = (const float*)d_in[0];
  const float* SP  = (const float*)d_in[1];
  const float* SQ  = (const float*)d_in[2];
  const float* W21 = (const float*)d_in[3];
  const float* b21 = (const float*)d_in[4];
  const float* W22 = (const float*)d_in[5];
  const float* b22 = (const float*)d_in[6];
  const float* W23 = (const float*)d_in[7];
  const float* b23 = (const float*)d_in[8];
  const float* W24 = (const float*)d_in[9];
  const float* b24 = (const float*)d_in[10];
  const float* W25 = (const float*)d_in[11];
  const float* b25 = (const float*)d_in[12];
  float* out = (float*)d_out;

  dim3 grid(5000), block(512);
  hipLaunchKernelGGL(fused_attn_kernel, grid, block, 0, stream,
                     X, SP, SQ, W21, b21, W22, b22, W23, b23, W24, b24, W25, b25, out);
}